// Round 12
// baseline (140.684 us; speedup 1.0000x reference)
//
#include <hip/hip_runtime.h>
#include <hip/hip_bf16.h>

// CrossAttentionOutLayer: out[b,i,j] = (1/H) * sum_c Q'[b,i,c] * K[b,j,c]
//   Q' = SCALE*(rna@Wq.T + bq) + rel_bias   (c = h*DK+d == flat rel_bias idx)
//   K  = prot@Wk.T + bk
// B=8 N=1024 M=1024 DIM2=1280 KIN=1344 H=8 DK=64 HDK=512 SCALE=0.125
//
// R12: NO-LDS direct-to-register proj. Control experiment: attn_kernel
// (m97 structure, bf16 gload_lds) = 896 TF; every reg-staged-cvt proj
// variant (R5-R11, six schedules) = ~400 TF. The f32->cvt->LDS round trip
// IS the wall. New proj: fragments loaded straight from global into regs
// (A: 2x dwordx4 + cvt_pk per frag; W: pre-converted to bf16 by a tiny
// kernel, 1 dwordx4 per frag). Zero LDS, zero barriers in the K-loop;
// per-wave depth-2 half-step prefetch with counted WAITV(12) (R8's proven
// asm machinery). W reuse rides L1/L2 (2.7 MB, hot); A panel x4 col-blocks
// rides L2 via XCD swizzle.

typedef __bf16 bf16x8 __attribute__((ext_vector_type(8)));
typedef __bf16 bf16x4 __attribute__((ext_vector_type(4)));
typedef float f32x4 __attribute__((ext_vector_type(4)));

__device__ inline bf16x4 cvt4(const f32x4 a) {
    bf16x4 r;
    r[0] = (__bf16)a[0]; r[1] = (__bf16)a[1];
    r[2] = (__bf16)a[2]; r[3] = (__bf16)a[3];
    return r;
}

__device__ inline bf16x8 cvt2(const f32x4 a, const f32x4 b) {
    bf16x8 r;
    r[0] = (__bf16)a[0]; r[1] = (__bf16)a[1]; r[2] = (__bf16)a[2]; r[3] = (__bf16)a[3];
    r[4] = (__bf16)b[0]; r[5] = (__bf16)b[1]; r[6] = (__bf16)b[2]; r[7] = (__bf16)b[3];
    return r;
}

// unsinkable 16B global loads; dst EARLY-CLOBBER (never aliases addr regs).
// NO implicit wait — caller must s_waitcnt vmcnt before reading dst.
__device__ inline void gload4(f32x4& dst, const float* p) {
    asm volatile("global_load_dwordx4 %0, %1, off"
                 : "=&v"(dst) : "v"(p) : "memory");
}
__device__ inline void gload4b(bf16x8& dst, const __bf16* p) {
    asm volatile("global_load_dwordx4 %0, %1, off"
                 : "=&v"(dst) : "v"(p) : "memory");
}

#define SCHB  __builtin_amdgcn_sched_barrier(0)
#define WAITV(n_) asm volatile("s_waitcnt vmcnt(" #n_ ")" ::: "memory")

// ---------------------------------------------------------------------------
// Weight pre-convert: Wq,Wk f32 -> bf16 (same [out,K] layout). 1.34M elems.
// ---------------------------------------------------------------------------
__global__ __launch_bounds__(256)
void wcvt(const float* __restrict__ Wq, const float* __restrict__ Wk,
          __bf16* __restrict__ wqb, __bf16* __restrict__ wkb)
{
    const int NQ = 512 * 1280 / 4;           // f32x4 slots in Wq
    const int s  = blockIdx.x * 256 + threadIdx.x;
    if (s < NQ) {
        ((bf16x4*)wqb)[s] = cvt4(((const f32x4*)Wq)[s]);
    } else {
        const int t = s - NQ;                // 512*1344/4 slots in Wk
        ((bf16x4*)wkb)[t] = cvt4(((const f32x4*)Wk)[t]);
    }
}

// ---------------------------------------------------------------------------
// Fused Q+K projection, no-LDS. Tile 128x128, 4 waves (2x2) of 64x64.
// Phase = half K-step (32 f32 of k). U = K/32 phases (40 or 42, even).
// Per phase per wave: 8 A-loads (f32) + 4 W-loads (bf16) -> WAITV(12)
// counted (phase u+1 stays in flight) -> 16 cvt_pk -> 16 MFMA.
// grid 512 (2 blocks/CU), bijective XCD swizzle.
// ---------------------------------------------------------------------------
__global__ __launch_bounds__(256, 2)
void proj_all(const float* __restrict__ rna,  const float* __restrict__ prot,
              const __bf16* __restrict__ wqb, const __bf16* __restrict__ wkb,
              const float* __restrict__ bq,   const float* __restrict__ bk,
              const float* __restrict__ rb,
              __bf16* __restrict__ qout, __bf16* __restrict__ kout)
{
    const int bid = blockIdx.x;
    const int wg  = (bid & 7) * 64 + (bid >> 3);   // bijective XCD swizzle (512%8==0)
    const bool isQ = wg < 256;
    const int lwg  = isQ ? wg : wg - 256;
    const int brow = (lwg >> 2) * 128;
    const int bcol = (lwg & 3) * 128;

    const float*  A    = isQ ? rna : prot;
    const __bf16* Wb   = isQ ? wqb : wkb;
    const float*  bias = isQ ? bq  : bk;
    __bf16*       out  = isQ ? qout : kout;
    const int     K    = isQ ? 1280 : 1344;
    const int     U    = K >> 5;          // 40 (Q) or 42 (K) phases, always even

    const int tid  = threadIdx.x;
    const int lane = tid & 63;
    const int wid  = tid >> 6;
    const int wr   = wid >> 1;
    const int wc   = wid & 1;
    const int fr   = lane & 15;
    const int q4   = lane >> 4;

    // per-lane fragment base pointers (k-offset q4*8 within each 32-elem phase)
    const float*  aB0 = A  + (size_t)(brow + wr * 64 +  0 + fr) * K + q4 * 8;
    const float*  aB1 = A  + (size_t)(brow + wr * 64 + 16 + fr) * K + q4 * 8;
    const float*  aB2 = A  + (size_t)(brow + wr * 64 + 32 + fr) * K + q4 * 8;
    const float*  aB3 = A  + (size_t)(brow + wr * 64 + 48 + fr) * K + q4 * 8;
    const __bf16* wB0 = Wb + (size_t)(bcol + wc * 64 +  0 + fr) * K + q4 * 8;
    const __bf16* wB1 = Wb + (size_t)(bcol + wc * 64 + 16 + fr) * K + q4 * 8;
    const __bf16* wB2 = Wb + (size_t)(bcol + wc * 64 + 32 + fr) * K + q4 * 8;
    const __bf16* wB3 = Wb + (size_t)(bcol + wc * 64 + 48 + fr) * K + q4 * 8;

    f32x4  acc[4][4] = {};
    f32x4  sa0[8], sa1[8];               // two named A half-sets (f32)
    bf16x8 sw0[4], sw1[4];               // two named W half-sets (bf16)

#define MM(m_, n_, A_, B_) acc[m_][n_] = __builtin_amdgcn_mfma_f32_16x16x32_bf16(A_, B_, acc[m_][n_], 0, 0, 0)

// issue the 12 loads of phase u_ (FIFO order: A0..A7 then W0..W3)
#define ISSUE(u_, sa, sw) do {                                            \
    const int ko_ = (u_) * 32;                                            \
    gload4(sa[0], aB0 + ko_); gload4(sa[1], aB0 + ko_ + 4);               \
    gload4(sa[2], aB1 + ko_); gload4(sa[3], aB1 + ko_ + 4);               \
    gload4(sa[4], aB2 + ko_); gload4(sa[5], aB2 + ko_ + 4);               \
    gload4(sa[6], aB3 + ko_); gload4(sa[7], aB3 + ko_ + 4);               \
    gload4b(sw[0], wB0 + ko_); gload4b(sw[1], wB1 + ko_);                 \
    gload4b(sw[2], wB2 + ko_); gload4b(sw[3], wB3 + ko_);                 \
} while (0)

// PHASE(u): at entry, outstanding = [phase u: 12, phase u+1: 12].
// WAITV(12) retires u's loads, keeps u+1 in flight (T4: never drain).
// SCHB fences cvt/MFMA below the wait (rule #18). ISSUE(u+2) placed after
// the MFMAs (in-order issue; WAR on sa/sw respected via asm redefinition).
#define PHASE(u_, sa, sw) do {                                            \
    if ((u_) + 1 < U) { WAITV(12); } else { WAITV(0); }                   \
    SCHB;                                                                 \
    bf16x8 a0_ = cvt2(sa[0], sa[1]), a1_ = cvt2(sa[2], sa[3]);            \
    bf16x8 a2_ = cvt2(sa[4], sa[5]), a3_ = cvt2(sa[6], sa[7]);            \
    __builtin_amdgcn_s_setprio(1);                                        \
    MM(0, 0, a0_, sw[0]); MM(1, 0, a1_, sw[0]); MM(2, 0, a2_, sw[0]); MM(3, 0, a3_, sw[0]); \
    MM(0, 1, a0_, sw[1]); MM(1, 1, a1_, sw[1]); MM(2, 1, a2_, sw[1]); MM(3, 1, a3_, sw[1]); \
    MM(0, 2, a0_, sw[2]); MM(1, 2, a1_, sw[2]); MM(2, 2, a2_, sw[2]); MM(3, 2, a3_, sw[2]); \
    MM(0, 3, a0_, sw[3]); MM(1, 3, a1_, sw[3]); MM(2, 3, a2_, sw[3]); MM(3, 3, a3_, sw[3]); \
    __builtin_amdgcn_s_setprio(0);                                        \
    if ((u_) + 2 < U) ISSUE((u_) + 2, sa, sw);                            \
} while (0)

    // prologue: phases 0 and 1 in flight
    ISSUE(0, sa0, sw0);
    ISSUE(1, sa1, sw1);

    for (int u = 0; u < U; u += 2) {     // pair-unroll keeps sets static
        PHASE(u,     sa0, sw0);
        PHASE(u + 1, sa1, sw1);
    }

#undef ISSUE
#undef PHASE
#undef MM

    // C/D layout: col = lane&15, row = (lane>>4)*4 + j  [m89-verified]
    const int r0 = q4 * 4;
    #pragma unroll
    for (int n = 0; n < 4; ++n) {
        const int c = bcol + wc * 64 + n * 16 + fr;
        const float bv = bias[c];
        const float rv = isQ ? rb[c] : 0.0f;
        #pragma unroll
        for (int m = 0; m < 4; ++m) {
            const int row = brow + wr * 64 + m * 16 + r0;
            #pragma unroll
            for (int j = 0; j < 4; ++j) {
                float v = acc[m][n][j] + bv;
                if (isQ) v = 0.125f * v + rv;
                out[(size_t)(row + j) * 512 + c] = (__bf16)v;
            }
        }
    }
}

// ---------------------------------------------------------------------------
// Batched GEMM: out[b,i,j] = 0.125 * sum_c Q[b,i,c]*K[b,j,c]
// 128x128 tile, BK=64, gload_lds staging, swizzled bf16 LDS. (unchanged;
// ~896 TF ~= m97-class, near its HBM/structure floor)
// ---------------------------------------------------------------------------
__global__ __launch_bounds__(256, 2)
void attn_kernel(const __bf16* __restrict__ Q,
                 const __bf16* __restrict__ Kb,
                 float* __restrict__ out)
{
    __shared__ __bf16 As[128 * 64];   // 16 KB, linear dest (swizzled content)
    __shared__ __bf16 Bs[128 * 64];

    const int tid  = threadIdx.x;
    const int lane = tid & 63;
    const int wid  = tid >> 6;
    const int wr   = wid >> 1;
    const int wc   = wid & 1;
    const int b    = blockIdx.z;
    const int brow = blockIdx.y * 128;
    const int bcol = blockIdx.x * 128;

    const __bf16* Qb = Q  + (size_t)b * 1024 * 512;
    const __bf16* Kp = Kb + (size_t)b * 1024 * 512;

    const int fr = lane & 15;
    const int q4 = lane >> 4;

    f32x4 acc[4][4] = {};

    const int lr3 = lane >> 3;
    const int m3  = ((lr3 & 3) << 1) | ((lr3 >> 2) & 1);
    const int scol = ((lane & 7) ^ m3) * 8;            // swizzled global bf16 col
    const int rmask = ((fr & 3) << 1) | ((fr >> 2) & 1);

    for (int k0 = 0; k0 < 512; k0 += 64) {
        __syncthreads();
        #pragma unroll
        for (int i = 0; i < 4; ++i) {
            const int rbase = wid * 32 + i * 8;
            const __bf16* sa = Qb + (size_t)(brow + rbase + lr3) * 512 + k0 + scol;
            const __bf16* sb = Kp + (size_t)(bcol + rbase + lr3) * 512 + k0 + scol;
            __builtin_amdgcn_global_load_lds(
                (const __attribute__((address_space(1))) void*)sa,
                (__attribute__((address_space(3))) void*)&As[rbase * 64], 16, 0, 0);
            __builtin_amdgcn_global_load_lds(
                (const __attribute__((address_space(1))) void*)sb,
                (__attribute__((address_space(3))) void*)&Bs[rbase * 64], 16, 0, 0);
        }
        __syncthreads();

        #pragma unroll
        for (int kk = 0; kk < 2; ++kk) {
            const int ci = kk * 4 + q4;
            bf16x8 af[4], bf_[4];
            #pragma unroll
            for (int m = 0; m < 4; ++m)
                af[m] = *(const bf16x8*)(&As[(wr * 64 + m * 16 + fr) * 64 + ((ci ^ rmask) << 3)]);
            #pragma unroll
            for (int n = 0; n < 4; ++n)
                bf_[n] = *(const bf16x8*)(&Bs[(wc * 64 + n * 16 + fr) * 64 + ((ci ^ rmask) << 3)]);
            #pragma unroll
            for (int m = 0; m < 4; ++m)
                #pragma unroll
                for (int n = 0; n < 4; ++n)
                    acc[m][n] = __builtin_amdgcn_mfma_f32_16x16x32_bf16(af[m], bf_[n], acc[m][n], 0, 0, 0);
        }
    }

    float* op = out + (size_t)b * 1024 * 1024;
    const int r0 = (lane >> 4) * 4;
    #pragma unroll
    for (int n = 0; n < 4; ++n) {
        const int col = bcol + wc * 64 + n * 16 + fr;
        #pragma unroll
        for (int m = 0; m < 4; ++m) {
            const int row = brow + wr * 64 + m * 16 + r0;
            #pragma unroll
            for (int j = 0; j < 4; ++j)
                op[(size_t)(row + j) * 1024 + col] = 0.125f * acc[m][n][j];
        }
    }
}

extern "C" void kernel_launch(void* const* d_in, const int* in_sizes, int n_in,
                              void* d_out, int out_size, void* d_ws, size_t ws_size,
                              hipStream_t stream) {
    const float* rna  = (const float*)d_in[0];  // [8,1024,1280]
    const float* prot = (const float*)d_in[1];  // [8,1024,1344]
    const float* Wq   = (const float*)d_in[2];  // [512,1280]
    const float* bq   = (const float*)d_in[3];  // [512]
    const float* Wk   = (const float*)d_in[4];  // [512,1344]
    const float* bk   = (const float*)d_in[5];  // [512]
    const float* rb   = (const float*)d_in[6];  // [512] (flat idx == channel)

    __bf16* qws = (__bf16*)d_ws;                     // [8192,512] bf16 = 8 MB
    __bf16* kws = qws + (size_t)8192 * 512;          // [8192,512] bf16 = 8 MB
    __bf16* wqb = kws + (size_t)8192 * 512;          // [512,1280] bf16 = 1.25 MB
    __bf16* wkb = wqb + (size_t)512 * 1280;          // [512,1344] bf16 = 1.31 MB

    // total slots = (512*1280 + 512*1344)/4 = 335872 = 1312 * 256
    wcvt<<<dim3(1312), dim3(256), 0, stream>>>(Wq, Wk, wqb, wkb);
    proj_all<<<dim3(512), dim3(256), 0, stream>>>(rna, prot, wqb, wkb, bq, bk, rb, qws, kws);
    attn_kernel<<<dim3(8, 8, 8), dim3(256), 0, stream>>>(qws, kws, (float*)d_out);
}

// Round 13
// 63.673 us; speedup vs baseline: 2.2095x; 2.2095x over previous
//
#include <hip/hip_runtime.h>
#include <hip/hip_bf16.h>

// CrossAttentionOutLayer: out[b,i,j] = (1/H) * sum_c Q'[b,i,c] * K[b,j,c]
//   Q' = SCALE*(rna@Wq.T + bq) + rel_bias   (c = h*DK+d == flat rel_bias idx)
//   K  = prot@Wk.T + bk
// B=8 N=1024 M=1024 DIM2=1280 KIN=1344 H=8 DK=64 HDK=512 SCALE=0.125
//
// R13: proj as attn-clone (gload_lds for BOTH operands). Evidence: attn
// (gload_lds skeleton) = 896 TF in this session; reg-staged-cvt proj capped
// at ~420 TF over six schedules (R5-R11); per-lane direct loads = 180 TF
// (R12: scattered 16-row x 32B pattern, ~64 requests/instr). So: W is
// pre-converted to bf16 AND pre-swizzled in HBM by wcvt (LDS swizzle baked
// into memory -> gload_lds stays linear, rule #21 by construction); A is
// staged f32 via gload_lds with R4's proven per-lane source-col swizzle and
// converted to bf16 at fragment-read (2x ds_read_b128 + pk-cvt).
// Geometry: BM=64 x BN=256 x BK=64, 8 waves (each 64x32), LDS 48KB ->
// 2 blocks/CU co-resident (m97/m114 overlap). Plain __syncthreads (m97).

typedef __bf16 bf16x8 __attribute__((ext_vector_type(8)));
typedef float f32x4 __attribute__((ext_vector_type(4)));

__device__ inline bf16x8 cvt2(const f32x4 a, const f32x4 b) {
    bf16x8 r;
    r[0] = (__bf16)a[0]; r[1] = (__bf16)a[1]; r[2] = (__bf16)a[2]; r[3] = (__bf16)a[3];
    r[4] = (__bf16)b[0]; r[5] = (__bf16)b[1]; r[6] = (__bf16)b[2]; r[7] = (__bf16)b[3];
    return r;
}

#define GLDS(src, dst) __builtin_amdgcn_global_load_lds( \
    (const __attribute__((address_space(1))) void*)(src), \
    (__attribute__((address_space(3))) void*)(dst), 16, 0, 0)

// ---------------------------------------------------------------------------
// Weight convert + swizzle: wb[row][p] = orig[row][(p&~7) | ((p&7)^m3(row&7))]
// (bf16, 16B chunks). m3(r) = ((r&3)<<1)|((r>>2)&1). Baking the XOR into HBM
// makes the gload_lds-staged LDS tile conflict-free under the standard
// fragment-read XOR. chunks: Wq 512x160, Wk 512x168; total 167936 = 656*256.
// ---------------------------------------------------------------------------
__global__ __launch_bounds__(256)
void wcvt(const float* __restrict__ Wq, const float* __restrict__ Wk,
          __bf16* __restrict__ wqb, __bf16* __restrict__ wkb)
{
    const int id = blockIdx.x * 256 + threadIdx.x;
    const int NQ = 512 * 160;
    const float* src; __bf16* dst; int row, p, K;
    if (id < NQ) { row = id / 160; p = id - row * 160; K = 1280; src = Wq; dst = wqb; }
    else { const int t = id - NQ; row = t / 168; p = t - row * 168; K = 1344; src = Wk; dst = wkb; }
    const int m3 = ((row & 3) << 1) | ((row >> 2) & 1);
    const int c  = (p & ~7) | ((p & 7) ^ m3);
    const f32x4 v0 = *(const f32x4*)(src + (size_t)row * K + c * 8);
    const f32x4 v1 = *(const f32x4*)(src + (size_t)row * K + c * 8 + 4);
    *(bf16x8*)(dst + (size_t)row * K + p * 8) = cvt2(v0, v1);
}

// ---------------------------------------------------------------------------
// Fused Q+K projection. BM=64 x BN=256 x BK=64; 8 waves, each 64x32 out.
// A: f32 in LDS (gload_lds, source-col swizzled); W: bf16 in LDS (gload_lds,
// pre-swizzled in HBM by wcvt). grid 512 (2/CU), bijective XCD swizzle.
// ---------------------------------------------------------------------------
__global__ __launch_bounds__(512, 4)
void proj_all(const float* __restrict__ rna,  const float* __restrict__ prot,
              const __bf16* __restrict__ wqb, const __bf16* __restrict__ wkb,
              const float* __restrict__ bq,   const float* __restrict__ bk,
              const float* __restrict__ rb,
              __bf16* __restrict__ qout, __bf16* __restrict__ kout)
{
    __shared__ float  As[64 * 64];    // 16 KB (f32, swizzled content)
    __shared__ __bf16 Ws[256 * 64];   // 32 KB (bf16, swizzled content)

    const int bid = blockIdx.x;
    const int wg  = (bid & 7) * 64 + (bid >> 3);   // bijective XCD swizzle (512%8==0)
    const bool isQ = wg < 256;
    const int lwg  = isQ ? wg : wg - 256;
    const int brow = (lwg >> 1) * 64;    // 128 row-tiles per matrix
    const int bcol = (lwg & 1) * 256;    // 2 col-tiles (N=512)

    const float*  A    = isQ ? rna : prot;
    const __bf16* Wb   = isQ ? wqb : wkb;
    const float*  bias = isQ ? bq  : bk;
    __bf16*       out  = isQ ? qout : kout;
    const int     K    = isQ ? 1280 : 1344;

    const int tid  = threadIdx.x;
    const int lane = tid & 63;
    const int wid  = tid >> 6;           // 0..7
    const int fr   = lane & 15;
    const int q4   = lane >> 4;

    // ---- A staging (2 instrs/wave): instr e: rows wid*8 + 4e + lrow ----
    // per-lane source chunk swizzle (R4-proven): row&7 = 4e + lrow,
    // m3 = (lrow<<1)|e  ->  ci = (lane&15) ^ (lrow<<1)  (e=1: XOR 1).
    const int lrow = lane >> 4;
    const int ciA  = (lane & 15) ^ (lrow << 1);
    const float* aG0 = A + (size_t)(brow + wid * 8 + 0 + lrow) * K + ciA * 4;
    const float* aG1 = A + (size_t)(brow + wid * 8 + 4 + lrow) * K + (ciA ^ 1) * 4;

    // ---- W staging (4 instrs/wave): instr j: rows bcol + wid*32 + j*8 + (l>>3),
    // chunk l&7. Source already bf16+swizzled in HBM -> linear copy. ----
    const __bf16* wG = Wb + (size_t)(bcol + wid * 32 + (lane >> 3)) * K + (lane & 7) * 8;

    // fragment-read swizzle (frag row&7 = fr&7)
    const int rmask = ((fr & 3) << 1) | ((fr >> 2) & 1);

    f32x4 acc[4][2] = {};

    for (int k0 = 0; k0 < K; k0 += 64) {
        __syncthreads();                       // prev step's frag reads done
        GLDS(aG0 + k0, &As[wid * 512]);        // rows wid*8..+3
        GLDS(aG1 + k0, &As[wid * 512 + 256]);  // rows wid*8+4..+7
        #pragma unroll
        for (int j = 0; j < 4; ++j)
            GLDS(wG + (size_t)(j * 8) * K + k0, &Ws[(wid * 32 + j * 8) * 64]);
        __syncthreads();                       // drains vmcnt -> tiles resident

        #pragma unroll
        for (int kk = 0; kk < 2; ++kk) {
            const int c0 = kk * 8 + 2 * q4;    // A f32 chunk pair
            const int cw = kk * 4 + q4;        // W bf16 chunk
            bf16x8 af[4], bw[2];
            #pragma unroll
            for (int m = 0; m < 4; ++m) {
                const float* rp = &As[(m * 16 + fr) * 64];
                f32x4 u0 = *(const f32x4*)(rp + (((c0    ) ^ rmask) << 2));
                f32x4 u1 = *(const f32x4*)(rp + (((c0 + 1) ^ rmask) << 2));
                af[m] = cvt2(u0, u1);
            }
            #pragma unroll
            for (int n = 0; n < 2; ++n)
                bw[n] = *(const bf16x8*)(&Ws[(wid * 32 + n * 16 + fr) * 64
                                             + ((cw ^ rmask) << 3)]);
            #pragma unroll
            for (int m = 0; m < 4; ++m)
                #pragma unroll
                for (int n = 0; n < 2; ++n)
                    acc[m][n] = __builtin_amdgcn_mfma_f32_16x16x32_bf16(af[m], bw[n], acc[m][n], 0, 0, 0);
        }
    }

    // C/D layout: col = lane&15, row = (lane>>4)*4 + j  [m89-verified]
    const int r0 = q4 * 4;
    #pragma unroll
    for (int n = 0; n < 2; ++n) {
        const int c = bcol + wid * 32 + n * 16 + fr;
        const float bv = bias[c];
        const float rv = isQ ? rb[c] : 0.0f;
        #pragma unroll
        for (int m = 0; m < 4; ++m) {
            const int row = brow + m * 16 + r0;
            #pragma unroll
            for (int j = 0; j < 4; ++j) {
                float v = acc[m][n][j] + bv;
                if (isQ) v = 0.125f * v + rv;
                out[(size_t)(row + j) * 512 + c] = (__bf16)v;
            }
        }
    }
}

// ---------------------------------------------------------------------------
// Batched GEMM: out[b,i,j] = 0.125 * sum_c Q[b,i,c]*K[b,j,c]
// 128x128 tile, BK=64, gload_lds staging, swizzled bf16 LDS. (unchanged;
// ~896 TF, near its HBM/structure floor)
// ---------------------------------------------------------------------------
__global__ __launch_bounds__(256, 2)
void attn_kernel(const __bf16* __restrict__ Q,
                 const __bf16* __restrict__ Kb,
                 float* __restrict__ out)
{
    __shared__ __bf16 As[128 * 64];   // 16 KB, linear dest (swizzled content)
    __shared__ __bf16 Bs[128 * 64];

    const int tid  = threadIdx.x;
    const int lane = tid & 63;
    const int wid  = tid >> 6;
    const int wr   = wid >> 1;
    const int wc   = wid & 1;
    const int b    = blockIdx.z;
    const int brow = blockIdx.y * 128;
    const int bcol = blockIdx.x * 128;

    const __bf16* Qb = Q  + (size_t)b * 1024 * 512;
    const __bf16* Kp = Kb + (size_t)b * 1024 * 512;

    const int fr = lane & 15;
    const int q4 = lane >> 4;

    f32x4 acc[4][4] = {};

    const int lr3 = lane >> 3;
    const int m3  = ((lr3 & 3) << 1) | ((lr3 >> 2) & 1);
    const int scol = ((lane & 7) ^ m3) * 8;            // swizzled global bf16 col
    const int rmask = ((fr & 3) << 1) | ((fr >> 2) & 1);

    for (int k0 = 0; k0 < 512; k0 += 64) {
        __syncthreads();
        #pragma unroll
        for (int i = 0; i < 4; ++i) {
            const int rbase = wid * 32 + i * 8;
            GLDS(Qb + (size_t)(brow + rbase + lr3) * 512 + k0 + scol, &As[rbase * 64]);
            GLDS(Kp + (size_t)(bcol + rbase + lr3) * 512 + k0 + scol, &Bs[rbase * 64]);
        }
        __syncthreads();

        #pragma unroll
        for (int kk = 0; kk < 2; ++kk) {
            const int ci = kk * 4 + q4;
            bf16x8 af[4], bf_[4];
            #pragma unroll
            for (int m = 0; m < 4; ++m)
                af[m] = *(const bf16x8*)(&As[(wr * 64 + m * 16 + fr) * 64 + ((ci ^ rmask) << 3)]);
            #pragma unroll
            for (int n = 0; n < 4; ++n)
                bf_[n] = *(const bf16x8*)(&Bs[(wc * 64 + n * 16 + fr) * 64 + ((ci ^ rmask) << 3)]);
            #pragma unroll
            for (int m = 0; m < 4; ++m)
                #pragma unroll
                for (int n = 0; n < 4; ++n)
                    acc[m][n] = __builtin_amdgcn_mfma_f32_16x16x32_bf16(af[m], bf_[n], acc[m][n], 0, 0, 0);
        }
    }

    float* op = out + (size_t)b * 1024 * 1024;
    const int r0 = (lane >> 4) * 4;
    #pragma unroll
    for (int n = 0; n < 4; ++n) {
        const int col = bcol + wc * 64 + n * 16 + fr;
        #pragma unroll
        for (int m = 0; m < 4; ++m) {
            const int row = brow + wr * 64 + m * 16 + r0;
            #pragma unroll
            for (int j = 0; j < 4; ++j)
                op[(size_t)(row + j) * 1024 + col] = 0.125f * acc[m][n][j];
        }
    }
}

extern "C" void kernel_launch(void* const* d_in, const int* in_sizes, int n_in,
                              void* d_out, int out_size, void* d_ws, size_t ws_size,
                              hipStream_t stream) {
    const float* rna  = (const float*)d_in[0];  // [8,1024,1280]
    const float* prot = (const float*)d_in[1];  // [8,1024,1344]
    const float* Wq   = (const float*)d_in[2];  // [512,1280]
    const float* bq   = (const float*)d_in[3];  // [512]
    const float* Wk   = (const float*)d_in[4];  // [512,1344]
    const float* bk   = (const float*)d_in[5];  // [512]
    const float* rb   = (const float*)d_in[6];  // [512] (flat idx == channel)

    __bf16* qws = (__bf16*)d_ws;                     // [8192,512] bf16 = 8 MB
    __bf16* kws = qws + (size_t)8192 * 512;          // [8192,512] bf16 = 8 MB
    __bf16* wqb = kws + (size_t)8192 * 512;          // [512,1280] bf16 (swizzled)
    __bf16* wkb = wqb + (size_t)512 * 1280;          // [512,1344] bf16 (swizzled)

    // chunks = 512*(160+168) = 167936 = 656 * 256
    wcvt<<<dim3(656), dim3(256), 0, stream>>>(Wq, Wk, wqb, wkb);
    proj_all<<<dim3(512), dim3(512), 0, stream>>>(rna, prot, wqb, wkb, bq, bk, rb, qws, kws);
    attn_kernel<<<dim3(8, 8, 8), dim3(256), 0, stream>>>(qws, kws, (float*)d_out);
}